// Round 13
// baseline (189.322 us; speedup 1.0000x reference)
//
#include <hip/hip_runtime.h>
#include <math.h>

constexpr int Tn  = 512;
constexpr int Dn  = 512;   // DIM
constexpr int NH  = 8;
constexpr int DHn = 64;
constexpr int CL  = 16;    // chunk length
constexpr int NC  = Tn / CL; // 32 chunks
constexpr int NW  = Tn * Dn; // one 512x512 matrix
constexpr float EPSR = 1.1920929e-07f;

typedef __attribute__((ext_vector_type(8))) short bf16x8;
typedef __attribute__((ext_vector_type(4))) float f32x4;

static __device__ __forceinline__ float rdlane(float v, int l) {
  return __uint_as_float((unsigned)__builtin_amdgcn_readlane((int)__float_as_uint(v), l));
}
static __device__ __forceinline__ ushort f2bf(float f) {
  unsigned u = __float_as_uint(f);
  unsigned r = u + 0x7FFFu + ((u >> 16) & 1u);   // RNE
  return (ushort)(r >> 16);
}

// ---------------------------------------------------------------------------
// K1: pre RMSNorm + the three sigmoid gates (lr, decay, omega)
// ---------------------------------------------------------------------------
__global__ __launch_bounds__(256) void k_norm_gates(
    const float* __restrict__ x, const float* __restrict__ pw,
    const float* __restrict__ lrw, const float* __restrict__ lrb,
    const float* __restrict__ dw,  const float* __restrict__ db,
    const float* __restrict__ gw,  const float* __restrict__ gb,
    float* __restrict__ xn, float* __restrict__ wgt, float* __restrict__ dec)
{
  const int t = blockIdx.x;
  const int tid = threadIdx.x;
  const int lane = tid & 63, wid = tid >> 6;
  __shared__ float xrow[Dn];
  __shared__ float red[4];
  __shared__ float gl[24];

  float v0 = x[t*Dn + tid];
  float v1 = x[t*Dn + 256 + tid];
  float ss = v0*v0 + v1*v1;
  #pragma unroll
  for (int o = 1; o < 64; o <<= 1) ss += __shfl_xor(ss, o, 64);
  if (lane == 0) red[wid] = ss;
  __syncthreads();
  float ms = (red[0] + red[1] + red[2] + red[3]) * (1.0f / Dn);
  float sc = rsqrtf(ms + EPSR);
  float xn0 = v0 * sc * pw[tid];
  float xn1 = v1 * sc * pw[tid + 256];
  xrow[tid] = xn0; xrow[tid + 256] = xn1;
  xn[t*Dn + tid] = xn0; xn[t*Dn + 256 + tid] = xn1;
  __syncthreads();

  for (int g = wid; g < 24; g += 4) {
    const float* W = (g < 8) ? lrw : (g < 16) ? dw : gw;
    const int hh = g & 7;
    float acc = 0.f;
    #pragma unroll
    for (int j = 0; j < 8; ++j)
      acc += xrow[lane + j*64] * W[hh*Dn + lane + j*64];
    #pragma unroll
    for (int o = 1; o < 64; o <<= 1) acc += __shfl_xor(acc, o, 64);
    if (lane == 0) {
      float bias = ((g < 8) ? lrb : (g < 16) ? db : gb)[hh];
      gl[g] = 1.f / (1.f + __expf(-(acc + bias)));
    }
  }
  __syncthreads();
  if (tid < 8)        wgt[tid*Tn + t] = gl[16 + tid] * gl[tid];  // omega * lr
  else if (tid < 16)  dec[(tid - 8)*Tn + t] = gl[tid];           // decay
}

// ---------------------------------------------------------------------------
// K1b: fp32 -> bf16 weight conversion (Wq,Wk,Wv,Wo -> Wbf[4][262144])
// ---------------------------------------------------------------------------
__global__ __launch_bounds__(256) void k_cvt_w(
    const float* __restrict__ W0, const float* __restrict__ W1,
    const float* __restrict__ W2, const float* __restrict__ W3,
    ushort* __restrict__ ob)
{
  const float* W = (blockIdx.y == 0) ? W0 : (blockIdx.y == 1) ? W1
                 : (blockIdx.y == 2) ? W2 : W3;
  ushort* o = ob + (long)blockIdx.y * NW;
  const int i = (blockIdx.x * 256 + threadIdx.x) * 4;
  float4 v = *(const float4*)&W[i];
  ushort4 r;
  r.x = f2bf(v.x); r.y = f2bf(v.y); r.z = f2bf(v.z); r.w = f2bf(v.w);
  *(ushort4*)&o[i] = r;
}

// ---------------------------------------------------------------------------
// K2: depthwise conv1d (K=4), bf16 outputs (GEMM operands)
// ---------------------------------------------------------------------------
__global__ __launch_bounds__(512) void k_conv(
    const float* __restrict__ xn,
    const float* __restrict__ qcw, const float* __restrict__ kcw,
    const float* __restrict__ vcw,
    ushort* __restrict__ qin, ushort* __restrict__ kin, ushort* __restrict__ vin)
{
  const int t = blockIdx.x, c = threadIdx.x;
  float4 wq = *(const float4*)&qcw[c*4];
  float4 wk = *(const float4*)&kcw[c*4];
  float4 wv = *(const float4*)&vcw[c*4];
  float wqa[4] = {wq.x, wq.y, wq.z, wq.w};
  float wka[4] = {wk.x, wk.y, wk.z, wk.w};
  float wva[4] = {wv.x, wv.y, wv.z, wv.w};
  float aq = 0.f, ak = 0.f, av = 0.f;
  #pragma unroll
  for (int j = 0; j < 4; ++j) {
    int tt = t - 2 + j;
    if (tt >= 0 && tt < Tn) {
      float xv = xn[tt*Dn + c];
      aq = fmaf(xv, wqa[j], aq);
      ak = fmaf(xv, wka[j], ak);
      av = fmaf(xv, wva[j], av);
    }
  }
  qin[t*Dn + c] = f2bf(aq);
  kin[t*Dn + c] = f2bf(ak);
  vin[t*Dn + c] = f2bf(av);
}

// ---------------------------------------------------------------------------
// K3: bf16 MFMA NT GEMM, fp32 out:  C[m,n] = sum_k A[m,k]*B[n,k]  (512^3)
// grid (16, 8, nz), 128 thr (2 waves). No LDS (operands L2-resident).
// Fused per-head RMS (gamma != null, head == blockIdx.y since DH==64).
// ---------------------------------------------------------------------------
__global__ __launch_bounds__(128) void k_gemm_bf(
    const ushort* __restrict__ A0, long sA,
    const ushort* __restrict__ B0, long sB,
    float* __restrict__ C0, long sC,
    const float* __restrict__ gq, const float* __restrict__ gk)
{
  const int z = blockIdx.z;
  const ushort* A = A0 + (long)z * sA;
  const ushort* B = B0 + (long)z * sB;
  float* C = C0 + (long)z * sC;
  const int w = threadIdx.x >> 6, l = threadIdx.x & 63;
  const int m0 = blockIdx.x * 32 + w * 16;
  const int n0 = blockIdx.y * 64;
  const int lr = l & 15, lk = (l >> 4) * 8;
  const ushort* ap = A + (long)(m0 + lr) * 512 + lk;
  const ushort* bp = B + (long)(n0 + lr) * 512 + lk;

  f32x4 acc0 = {0.f,0.f,0.f,0.f}, acc1 = {0.f,0.f,0.f,0.f};
  f32x4 acc2 = {0.f,0.f,0.f,0.f}, acc3 = {0.f,0.f,0.f,0.f};
  #pragma unroll
  for (int k0 = 0; k0 < 512; k0 += 32) {
    bf16x8 a  = *(const bf16x8*)(ap + k0);
    bf16x8 b0 = *(const bf16x8*)(bp + k0);
    bf16x8 b1 = *(const bf16x8*)(bp + 16*512 + k0);
    bf16x8 b2 = *(const bf16x8*)(bp + 32*512 + k0);
    bf16x8 b3 = *(const bf16x8*)(bp + 48*512 + k0);
    acc0 = __builtin_amdgcn_mfma_f32_16x16x32_bf16(a, b0, acc0, 0, 0, 0);
    acc1 = __builtin_amdgcn_mfma_f32_16x16x32_bf16(a, b1, acc1, 0, 0, 0);
    acc2 = __builtin_amdgcn_mfma_f32_16x16x32_bf16(a, b2, acc2, 0, 0, 0);
    acc3 = __builtin_amdgcn_mfma_f32_16x16x32_bf16(a, b3, acc3, 0, 0, 0);
  }

  const float* gm = (z == 0) ? gq : (z == 1) ? gk : nullptr;
  if (gm != nullptr) {
    const float g0 = gm[n0 +  0 + lr], g1 = gm[n0 + 16 + lr];
    const float g2 = gm[n0 + 32 + lr], g3 = gm[n0 + 48 + lr];
    #pragma unroll
    for (int r = 0; r < 4; ++r) {
      float ss = acc0[r]*acc0[r] + acc1[r]*acc1[r]
               + acc2[r]*acc2[r] + acc3[r]*acc3[r];
      ss += __shfl_xor(ss, 1, 64); ss += __shfl_xor(ss, 2, 64);
      ss += __shfl_xor(ss, 4, 64); ss += __shfl_xor(ss, 8, 64);
      float inv = 1.f / fmaxf(sqrtf(ss) * 0.125f, 1e-8f);  // ||x||*64^-0.5
      acc0[r] *= inv * g0; acc1[r] *= inv * g1;
      acc2[r] *= inv * g2; acc3[r] *= inv * g3;
    }
  }
  const int rbase = m0 + (l >> 4) * 4;
  #pragma unroll
  for (int r = 0; r < 4; ++r) {
    C[(long)(rbase + r)*512 + n0 +  0 + lr] = acc0[r];
    C[(long)(rbase + r)*512 + n0 + 16 + lr] = acc1[r];
    C[(long)(rbase + r)*512 + n0 + 32 + lr] = acc2[r];
    C[(long)(rbase + r)*512 + n0 + 48 + lr] = acc3[r];
  }
}

// ---------------------------------------------------------------------------
// K5a: per-chunk local prefixes. Block (c,h), 512 threads, NO LDS / NO SYNC.
// Thread owns row=tid>>3, cols c0..c0+8 (c0=(tid&7)*8) of M (A-prefix,
// init I) and N (C-prefix, init 0). k-ring in registers kk[8][8] (64 VGPR
// footprint -> no rematerialization; was 128 at 4-lane split = 70us kernel).
// 3-level 8-lane shuffle reduces. 2048 waves = 2/SIMD (was 1/SIMD).
// ---------------------------------------------------------------------------
__global__ __launch_bounds__(512, 1) void k_chunk(
    const float* __restrict__ Qn, const float* __restrict__ Kn,
    const float* __restrict__ V,
    const float* __restrict__ wgt, const float* __restrict__ dec,
    float* __restrict__ Abar, float* __restrict__ Cbar,
    float* __restrict__ zbuf, float* __restrict__ cbuf)
{
  const int c = blockIdx.x, h = blockIdx.y;
  const int tid = threadIdx.x;
  const int row = tid >> 3, g = tid & 7, c0 = g * 8;

  float M[8], Nn[8], kk[8][8], vw[8], ww[8];
  #pragma unroll
  for (int j = 0; j < 8; ++j) {
    M[j] = (row == c0 + j) ? 1.f : 0.f;
    Nn[j] = 0.f;
  }
  #pragma unroll
  for (int j = 0; j < 8; ++j) kk[0][j] = 0.f;
  vw[0] = 0.f; ww[0] = 0.f;
  #pragma unroll
  for (int i = 0; i < 7; ++i) {
    const int t = c * CL - 7 + i;
    const int slot = i + 1;
    if (t >= 0) {
      const float4* kr = (const float4*)(Kn + (long)t*Dn + h*DHn + c0);
      *(float4*)&kk[slot][0] = kr[0];
      *(float4*)&kk[slot][4] = kr[1];
      vw[slot] = V[(long)t*Dn + h*DHn + row];
      ww[slot] = wgt[h*Tn + t];
    } else {
      #pragma unroll
      for (int j = 0; j < 8; ++j) kk[slot][j] = 0.f;
      vw[slot] = 0.f; ww[slot] = 0.f;
    }
  }

  for (int tb = 0; tb < 2; ++tb) {
    #pragma unroll
    for (int ii = 0; ii < 8; ++ii) {
      const int t = c * CL + tb * 8 + ii;
      // refresh ring slot ii (replaces t-8) with time t
      {
        const float4* kr = (const float4*)(Kn + (long)t*Dn + h*DHn + c0);
        *(float4*)&kk[ii][0] = kr[0];
        *(float4*)&kk[ii][4] = kr[1];
      }
      vw[ii] = V[(long)t*Dn + h*DHn + row];
      ww[ii] = wgt[h*Tn + t];
      const float dc = dec[h*Tn + t];

      // u-pass on OLD M,N
      float uM[8], uN[8];
      #pragma unroll
      for (int s = 0; s < 8; ++s) {
        float a = 0.f, b = 0.f;
        #pragma unroll
        for (int j = 0; j < 8; ++j) {
          a = fmaf(M[j], kk[s][j], a);
          b = fmaf(Nn[j], kk[s][j], b);
        }
        a += __shfl_xor(a, 1, 64); a += __shfl_xor(a, 2, 64);
        a += __shfl_xor(a, 4, 64);
        b += __shfl_xor(b, 1, 64); b += __shfl_xor(b, 2, 64);
        b += __shfl_xor(b, 4, 64);
        uM[s] = a; uN[s] = b;
      }
      // update
      #pragma unroll
      for (int j = 0; j < 8; ++j) { M[j] *= dc; Nn[j] *= dc; }
      #pragma unroll
      for (int s = 0; s < 8; ++s) {
        const float cM = -dc * ww[s] * uM[s];
        const float cN = ww[s] * (vw[s] - dc * uN[s]);
        #pragma unroll
        for (int j = 0; j < 8; ++j) {
          M[j]  = fmaf(cM, kk[s][j], M[j]);
          Nn[j] = fmaf(cN, kk[s][j], Nn[j]);
        }
      }
      // z_t = M q_t, chat_t = N q_t
      {
        float qv[8];
        const float4* qr = (const float4*)(Qn + (long)t*Dn + h*DHn + c0);
        *(float4*)&qv[0] = qr[0];
        *(float4*)&qv[4] = qr[1];
        float zp = 0.f, cp = 0.f;
        #pragma unroll
        for (int j = 0; j < 8; ++j) {
          zp = fmaf(M[j], qv[j], zp);
          cp = fmaf(Nn[j], qv[j], cp);
        }
        zp += __shfl_xor(zp, 1, 64); zp += __shfl_xor(zp, 2, 64);
        zp += __shfl_xor(zp, 4, 64);
        cp += __shfl_xor(cp, 1, 64); cp += __shfl_xor(cp, 2, 64);
        cp += __shfl_xor(cp, 4, 64);
        if (g == 0) {
          zbuf[((long)h*Tn + t)*DHn + row] = zp;
          cbuf[((long)h*Tn + t)*DHn + row] = cp;
        }
      }
    }
  }
  float* Ao = Abar + (((long)(c*NH + h)) * 64 + row) * 64 + c0;
  float* Co = Cbar + (((long)(c*NH + h)) * 64 + row) * 64 + c0;
  *(float4*)&Ao[0] = *(float4*)&M[0];
  *(float4*)&Ao[4] = *(float4*)&M[4];
  *(float4*)&Co[0] = *(float4*)&Nn[0];
  *(float4*)&Co[4] = *(float4*)&Nn[4];
}

// ---------------------------------------------------------------------------
// K5b: state-only chunk scan with register double-buffer prefetch.
// ---------------------------------------------------------------------------
__global__ __launch_bounds__(64, 1) void k_scan(
    const float* __restrict__ Abar, const float* __restrict__ Cbar,
    const float* __restrict__ S0, float* __restrict__ Sst)
{
  const int h = blockIdx.x >> 6, m = blockIdx.x & 63, d = threadIdx.x;
  float s = S0[((long)h*DHn + m)*DHn + d];
  float a0[64], a1[64];
  float cb0, cb1;

#define PREF_(AR, CB, CI) do { \
    const float* Ac_ = Abar + ((long)(CI)*NH + h) * 4096; \
    _Pragma("unroll") \
    for (int l = 0; l < 64; ++l) AR[l] = Ac_[l*64 + d]; \
    CB = Cbar[((long)(CI)*NH + h) * 4096 + m*64 + d]; \
  } while (0)

#define STEP_(AR, CB) do { \
    float n0 = 0.f, n1 = 0.f, n2 = 0.f, n3 = 0.f; \
    _Pragma("unroll") \
    for (int l = 0; l < 16; ++l) { \
      n0 = fmaf(rdlane(s, l),      AR[l],      n0); \
      n1 = fmaf(rdlane(s, 16 + l), AR[16 + l], n1); \
      n2 = fmaf(rdlane(s, 32 + l), AR[32 + l], n2); \
      n3 = fmaf(rdlane(s, 48 + l), AR[48 + l], n3); \
    } \
    s = ((n0 + n1) + (n2 + n3)) + CB; \
  } while (0)

  PREF_(a0, cb0, 0);
  #pragma unroll 1
  for (int c = 0; c < NC; c += 2) {
    PREF_(a1, cb1, c + 1);
    Sst[(((long)c*NH + h)*64 + m)*64 + d] = s;
    STEP_(a0, cb0);
    const int cn = (c + 2 < NC) ? (c + 2) : (NC - 1);
    PREF_(a0, cb0, cn);
    Sst[(((long)(c+1)*NH + h)*64 + m)*64 + d] = s;
    STEP_(a1, cb1);
  }
#undef PREF_
#undef STEP_
}

// ---------------------------------------------------------------------------
// K5c: parallel output eval -> bf16 Y (operand of the Wo GEMM).
// ---------------------------------------------------------------------------
__global__ __launch_bounds__(256, 1) void k_yout(
    const float* __restrict__ Sst, const float* __restrict__ zbuf,
    const float* __restrict__ cbuf, ushort* __restrict__ Y)
{
  const int c = blockIdx.x, h = blockIdx.y;
  const int tid = threadIdx.x, m = tid & 63, tg = tid >> 6;
  __shared__ float Zl[CL][DHn];
  {
    const float4* Zc = (const float4*)(zbuf + ((long)h*Tn + c*CL) * DHn);
    ((float4*)&Zl[0][0])[tid] = Zc[tid];
  }
  const float* Srow = Sst + (((long)c*NH + h)*64 + m) * 64;
  float sr[64];
  #pragma unroll
  for (int q4 = 0; q4 < 16; ++q4)
    *(float4*)&sr[q4*4] = ((const float4*)Srow)[q4];
  __syncthreads();
  const float* Cc = cbuf + ((long)h*Tn + c*CL) * DHn;
  #pragma unroll
  for (int it = 0; it < 4; ++it) {
    const int tt = tg*4 + it;
    float y = 0.f;
    #pragma unroll
    for (int l = 0; l < 64; ++l) y = fmaf(sr[l], Zl[tt][l], y);
    Y[((long)(c*CL + tt))*Dn + h*DHn + m] = f2bf(y + Cc[tt*DHn + m]);
  }
}

// ---------------------------------------------------------------------------
extern "C" void kernel_launch(void* const* d_in, const int* in_sizes, int n_in,
                              void* d_out, int out_size, void* d_ws, size_t ws_size,
                              hipStream_t stream)
{
  const float* x   = (const float*)d_in[0];
  const float* pw  = (const float*)d_in[1];
  const float* Wq  = (const float*)d_in[2];
  const float* Wk  = (const float*)d_in[3];
  const float* Wv  = (const float*)d_in[4];
  const float* Wo  = (const float*)d_in[5];
  const float* qcw = (const float*)d_in[6];
  const float* kcw = (const float*)d_in[7];
  const float* vcw = (const float*)d_in[8];
  const float* lrw = (const float*)d_in[9];
  const float* lrb = (const float*)d_in[10];
  const float* dw  = (const float*)d_in[11];
  const float* db  = (const float*)d_in[12];
  const float* gw  = (const float*)d_in[13];
  const float* gb  = (const float*)d_in[14];
  const float* qg  = (const float*)d_in[15];
  const float* kg  = (const float*)d_in[16];
  const float* S0  = (const float*)d_in[17];
  float* out = (float*)d_out;
  float* ws  = (float*)d_ws;

  const long N = (long)Tn * Dn;   // 262144 floats per 512x512 fp32 matrix
  float*  xn    = ws;
  ushort* qkvbf = (ushort*)(ws + 1*N);
  float*  Abar  = ws;
  float*  Cbar  = ws + 4*N;
  float*  Qb    = ws + 8*N;
  float*  Sst   = ws + 8*N;
  float*  zbuf  = ws + 12*N;
  float*  cbuf  = ws + 13*N;
  ushort* Wbf   = (ushort*)(ws + 14*N);
  ushort* Ybf   = (ushort*)(ws + 16*N);
  float*  wgt   = ws + 16*N + N/2;    // [NH][T]
  float*  dcb   = wgt + NH*Tn;        // [NH][T]

  k_norm_gates<<<Tn, 256, 0, stream>>>(x, pw, lrw, lrb, dw, db, gw, gb,
                                       xn, wgt, dcb);
  k_cvt_w<<<dim3(256, 4), 256, 0, stream>>>(Wq, Wk, Wv, Wo, Wbf);
  k_conv<<<Tn, Dn, 0, stream>>>(xn, qcw, kcw, vcw,
                                qkvbf, qkvbf + NW, qkvbf + 2*NW);
  k_gemm_bf<<<dim3(16, 8, 3), 128, 0, stream>>>(qkvbf, NW, Wbf, NW,
                                                Qb, N, qg, kg);
  k_chunk<<<dim3(NC, NH), 512, 0, stream>>>(Qb, Qb + N, Qb + 2*N, wgt, dcb,
                                            Abar, Cbar, zbuf, cbuf);
  k_scan<<<NH * DHn, 64, 0, stream>>>(Abar, Cbar, S0, Sst);
  k_yout<<<dim3(NC, NH), 256, 0, stream>>>(Sst, zbuf, cbuf, Ybf);
  k_gemm_bf<<<dim3(16, 8, 1), 128, 0, stream>>>(Ybf, 0, Wbf + 3*NW, 0,
                                                out, 0, nullptr, nullptr);
}

// Round 15
// 175.349 us; speedup vs baseline: 1.0797x; 1.0797x over previous
//
#include <hip/hip_runtime.h>
#include <math.h>

constexpr int Tn  = 512;
constexpr int Dn  = 512;   // DIM
constexpr int NH  = 8;
constexpr int DHn = 64;
constexpr int CL  = 16;    // chunk length
constexpr int NC  = Tn / CL; // 32 chunks
constexpr int NW  = Tn * Dn; // one 512x512 matrix
constexpr float EPSR = 1.1920929e-07f;

typedef __attribute__((ext_vector_type(8))) short bf16x8;
typedef __attribute__((ext_vector_type(4))) float f32x4;

static __device__ __forceinline__ float rdlane(float v, int l) {
  return __uint_as_float((unsigned)__builtin_amdgcn_readlane((int)__float_as_uint(v), l));
}
static __device__ __forceinline__ ushort f2bf(float f) {
  unsigned u = __float_as_uint(f);
  unsigned r = u + 0x7FFFu + ((u >> 16) & 1u);   // RNE
  return (ushort)(r >> 16);
}

// ---------------------------------------------------------------------------
// K1: pre RMSNorm + the three sigmoid gates (lr, decay, omega)
// ---------------------------------------------------------------------------
__global__ __launch_bounds__(256) void k_norm_gates(
    const float* __restrict__ x, const float* __restrict__ pw,
    const float* __restrict__ lrw, const float* __restrict__ lrb,
    const float* __restrict__ dw,  const float* __restrict__ db,
    const float* __restrict__ gw,  const float* __restrict__ gb,
    float* __restrict__ xn, float* __restrict__ wgt, float* __restrict__ dec)
{
  const int t = blockIdx.x;
  const int tid = threadIdx.x;
  const int lane = tid & 63, wid = tid >> 6;
  __shared__ float xrow[Dn];
  __shared__ float red[4];
  __shared__ float gl[24];

  float v0 = x[t*Dn + tid];
  float v1 = x[t*Dn + 256 + tid];
  float ss = v0*v0 + v1*v1;
  #pragma unroll
  for (int o = 1; o < 64; o <<= 1) ss += __shfl_xor(ss, o, 64);
  if (lane == 0) red[wid] = ss;
  __syncthreads();
  float ms = (red[0] + red[1] + red[2] + red[3]) * (1.0f / Dn);
  float sc = rsqrtf(ms + EPSR);
  float xn0 = v0 * sc * pw[tid];
  float xn1 = v1 * sc * pw[tid + 256];
  xrow[tid] = xn0; xrow[tid + 256] = xn1;
  xn[t*Dn + tid] = xn0; xn[t*Dn + 256 + tid] = xn1;
  __syncthreads();

  for (int g = wid; g < 24; g += 4) {
    const float* W = (g < 8) ? lrw : (g < 16) ? dw : gw;
    const int hh = g & 7;
    float acc = 0.f;
    #pragma unroll
    for (int j = 0; j < 8; ++j)
      acc += xrow[lane + j*64] * W[hh*Dn + lane + j*64];
    #pragma unroll
    for (int o = 1; o < 64; o <<= 1) acc += __shfl_xor(acc, o, 64);
    if (lane == 0) {
      float bias = ((g < 8) ? lrb : (g < 16) ? db : gb)[hh];
      gl[g] = 1.f / (1.f + __expf(-(acc + bias)));
    }
  }
  __syncthreads();
  if (tid < 8)        wgt[tid*Tn + t] = gl[16 + tid] * gl[tid];  // omega * lr
  else if (tid < 16)  dec[(tid - 8)*Tn + t] = gl[tid];           // decay
}

// ---------------------------------------------------------------------------
// K1b: fp32 -> bf16 weight conversion (Wq,Wk,Wv,Wo -> Wbf[4][262144])
// ---------------------------------------------------------------------------
__global__ __launch_bounds__(256) void k_cvt_w(
    const float* __restrict__ W0, const float* __restrict__ W1,
    const float* __restrict__ W2, const float* __restrict__ W3,
    ushort* __restrict__ ob)
{
  const float* W = (blockIdx.y == 0) ? W0 : (blockIdx.y == 1) ? W1
                 : (blockIdx.y == 2) ? W2 : W3;
  ushort* o = ob + (long)blockIdx.y * NW;
  const int i = (blockIdx.x * 256 + threadIdx.x) * 4;
  float4 v = *(const float4*)&W[i];
  ushort4 r;
  r.x = f2bf(v.x); r.y = f2bf(v.y); r.z = f2bf(v.z); r.w = f2bf(v.w);
  *(ushort4*)&o[i] = r;
}

// ---------------------------------------------------------------------------
// K2: depthwise conv1d (K=4), bf16 outputs (GEMM operands)
// ---------------------------------------------------------------------------
__global__ __launch_bounds__(512) void k_conv(
    const float* __restrict__ xn,
    const float* __restrict__ qcw, const float* __restrict__ kcw,
    const float* __restrict__ vcw,
    ushort* __restrict__ qin, ushort* __restrict__ kin, ushort* __restrict__ vin)
{
  const int t = blockIdx.x, c = threadIdx.x;
  float4 wq = *(const float4*)&qcw[c*4];
  float4 wk = *(const float4*)&kcw[c*4];
  float4 wv = *(const float4*)&vcw[c*4];
  float wqa[4] = {wq.x, wq.y, wq.z, wq.w};
  float wka[4] = {wk.x, wk.y, wk.z, wk.w};
  float wva[4] = {wv.x, wv.y, wv.z, wv.w};
  float aq = 0.f, ak = 0.f, av = 0.f;
  #pragma unroll
  for (int j = 0; j < 4; ++j) {
    int tt = t - 2 + j;
    if (tt >= 0 && tt < Tn) {
      float xv = xn[tt*Dn + c];
      aq = fmaf(xv, wqa[j], aq);
      ak = fmaf(xv, wka[j], ak);
      av = fmaf(xv, wva[j], av);
    }
  }
  qin[t*Dn + c] = f2bf(aq);
  kin[t*Dn + c] = f2bf(ak);
  vin[t*Dn + c] = f2bf(av);
}

// ---------------------------------------------------------------------------
// K3: bf16 MFMA NT GEMM, fp32 out:  C[m,n] = sum_k A[m,k]*B[n,k]  (512^3)
// grid (16, 8, nz), 128 thr (2 waves). No LDS (operands L2-resident).
// Fused per-head RMS (gamma != null, head == blockIdx.y since DH==64).
// ---------------------------------------------------------------------------
__global__ __launch_bounds__(128) void k_gemm_bf(
    const ushort* __restrict__ A0, long sA,
    const ushort* __restrict__ B0, long sB,
    float* __restrict__ C0, long sC,
    const float* __restrict__ gq, const float* __restrict__ gk)
{
  const int z = blockIdx.z;
  const ushort* A = A0 + (long)z * sA;
  const ushort* B = B0 + (long)z * sB;
  float* C = C0 + (long)z * sC;
  const int w = threadIdx.x >> 6, l = threadIdx.x & 63;
  const int m0 = blockIdx.x * 32 + w * 16;
  const int n0 = blockIdx.y * 64;
  const int lr = l & 15, lk = (l >> 4) * 8;
  const ushort* ap = A + (long)(m0 + lr) * 512 + lk;
  const ushort* bp = B + (long)(n0 + lr) * 512 + lk;

  f32x4 acc0 = {0.f,0.f,0.f,0.f}, acc1 = {0.f,0.f,0.f,0.f};
  f32x4 acc2 = {0.f,0.f,0.f,0.f}, acc3 = {0.f,0.f,0.f,0.f};
  #pragma unroll
  for (int k0 = 0; k0 < 512; k0 += 32) {
    bf16x8 a  = *(const bf16x8*)(ap + k0);
    bf16x8 b0 = *(const bf16x8*)(bp + k0);
    bf16x8 b1 = *(const bf16x8*)(bp + 16*512 + k0);
    bf16x8 b2 = *(const bf16x8*)(bp + 32*512 + k0);
    bf16x8 b3 = *(const bf16x8*)(bp + 48*512 + k0);
    acc0 = __builtin_amdgcn_mfma_f32_16x16x32_bf16(a, b0, acc0, 0, 0, 0);
    acc1 = __builtin_amdgcn_mfma_f32_16x16x32_bf16(a, b1, acc1, 0, 0, 0);
    acc2 = __builtin_amdgcn_mfma_f32_16x16x32_bf16(a, b2, acc2, 0, 0, 0);
    acc3 = __builtin_amdgcn_mfma_f32_16x16x32_bf16(a, b3, acc3, 0, 0, 0);
  }

  const float* gm = (z == 0) ? gq : (z == 1) ? gk : nullptr;
  if (gm != nullptr) {
    const float g0 = gm[n0 +  0 + lr], g1 = gm[n0 + 16 + lr];
    const float g2 = gm[n0 + 32 + lr], g3 = gm[n0 + 48 + lr];
    #pragma unroll
    for (int r = 0; r < 4; ++r) {
      float ss = acc0[r]*acc0[r] + acc1[r]*acc1[r]
               + acc2[r]*acc2[r] + acc3[r]*acc3[r];
      ss += __shfl_xor(ss, 1, 64); ss += __shfl_xor(ss, 2, 64);
      ss += __shfl_xor(ss, 4, 64); ss += __shfl_xor(ss, 8, 64);
      float inv = 1.f / fmaxf(sqrtf(ss) * 0.125f, 1e-8f);  // ||x||*64^-0.5
      acc0[r] *= inv * g0; acc1[r] *= inv * g1;
      acc2[r] *= inv * g2; acc3[r] *= inv * g3;
    }
  }
  const int rbase = m0 + (l >> 4) * 4;
  #pragma unroll
  for (int r = 0; r < 4; ++r) {
    C[(long)(rbase + r)*512 + n0 +  0 + lr] = acc0[r];
    C[(long)(rbase + r)*512 + n0 + 16 + lr] = acc1[r];
    C[(long)(rbase + r)*512 + n0 + 32 + lr] = acc2[r];
    C[(long)(rbase + r)*512 + n0 + 48 + lr] = acc3[r];
  }
}

// ---------------------------------------------------------------------------
// K5a: per-chunk local prefixes. Block (c,h), 512 threads.
// LDS-staged operands: the whole block shares K/V rows t0..t0+22
// (t0 = c*16-7) and window weights -> Ks/Vs/wgs staged once, 1 barrier.
// Per step: 8-slot window read from LDS (16 ds_read_b128 + 16 b32),
// compute in registers. Thread owns row=tid>>3, cols (tid&7)*8..+8.
// (R13 evidence: global-operand version had VGPR=68 with L2 reloads on
// the dependent chain -> 30% VALUBusy, 50us. LDS keeps reloads cheap.)
// ---------------------------------------------------------------------------
__global__ __launch_bounds__(512, 1) void k_chunk(
    const float* __restrict__ Qn, const float* __restrict__ Kn,
    const float* __restrict__ V,
    const float* __restrict__ wgt, const float* __restrict__ dec,
    float* __restrict__ Abar, float* __restrict__ Cbar,
    float* __restrict__ zbuf, float* __restrict__ cbuf)
{
  const int c = blockIdx.x, h = blockIdx.y;
  const int tid = threadIdx.x;
  const int row = tid >> 3, g = tid & 7, c0 = g * 8;
  const int t0 = c * CL - 7;

  __shared__ float Ks[23][64];
  __shared__ float Vs[23][64];
  __shared__ float wgs[23];

  for (int i = tid; i < 23 * 64; i += 512) {
    const int r = i >> 6, d = i & 63;
    const int t = t0 + r;
    float kv = 0.f, vv = 0.f;
    if (t >= 0) {
      kv = Kn[(long)t*Dn + h*DHn + d];
      vv = V [(long)t*Dn + h*DHn + d];
    }
    Ks[r][d] = kv;
    Vs[r][d] = vv;
  }
  if (tid < 23) {
    const int t = t0 + tid;
    wgs[tid] = (t >= 0) ? wgt[h*Tn + t] : 0.f;
  }
  __syncthreads();

  float M[8], Nn[8];
  #pragma unroll
  for (int j = 0; j < 8; ++j) {
    M[j] = (row == c0 + j) ? 1.f : 0.f;
    Nn[j] = 0.f;
  }

  #pragma unroll
  for (int ii = 0; ii < CL; ++ii) {
    const int t = c * CL + ii;
    const float dc = dec[h*Tn + t];
    // window slots s=0..7 = times t-7..t = LDS rows ii..ii+7
    float kk[8][8], vw[8], ww[8];
    #pragma unroll
    for (int s = 0; s < 8; ++s) {
      *(float4*)&kk[s][0] = *(const float4*)&Ks[ii + s][c0];
      *(float4*)&kk[s][4] = *(const float4*)&Ks[ii + s][c0 + 4];
      vw[s] = Vs[ii + s][row];
      ww[s] = wgs[ii + s];
    }

    // u-pass on OLD M,N
    float uM[8], uN[8];
    #pragma unroll
    for (int s = 0; s < 8; ++s) {
      float a = 0.f, b = 0.f;
      #pragma unroll
      for (int j = 0; j < 8; ++j) {
        a = fmaf(M[j], kk[s][j], a);
        b = fmaf(Nn[j], kk[s][j], b);
      }
      a += __shfl_xor(a, 1, 64); a += __shfl_xor(a, 2, 64);
      a += __shfl_xor(a, 4, 64);
      b += __shfl_xor(b, 1, 64); b += __shfl_xor(b, 2, 64);
      b += __shfl_xor(b, 4, 64);
      uM[s] = a; uN[s] = b;
    }
    // update
    #pragma unroll
    for (int j = 0; j < 8; ++j) { M[j] *= dc; Nn[j] *= dc; }
    #pragma unroll
    for (int s = 0; s < 8; ++s) {
      const float cM = -dc * ww[s] * uM[s];
      const float cN = ww[s] * (vw[s] - dc * uN[s]);
      #pragma unroll
      for (int j = 0; j < 8; ++j) {
        M[j]  = fmaf(cM, kk[s][j], M[j]);
        Nn[j] = fmaf(cN, kk[s][j], Nn[j]);
      }
    }
    // z_t = M q_t, chat_t = N q_t
    {
      float qv[8];
      const float4* qr = (const float4*)(Qn + (long)t*Dn + h*DHn + c0);
      *(float4*)&qv[0] = qr[0];
      *(float4*)&qv[4] = qr[1];
      float zp = 0.f, cp = 0.f;
      #pragma unroll
      for (int j = 0; j < 8; ++j) {
        zp = fmaf(M[j], qv[j], zp);
        cp = fmaf(Nn[j], qv[j], cp);
      }
      zp += __shfl_xor(zp, 1, 64); zp += __shfl_xor(zp, 2, 64);
      zp += __shfl_xor(zp, 4, 64);
      cp += __shfl_xor(cp, 1, 64); cp += __shfl_xor(cp, 2, 64);
      cp += __shfl_xor(cp, 4, 64);
      if (g == 0) {
        zbuf[((long)h*Tn + t)*DHn + row] = zp;
        cbuf[((long)h*Tn + t)*DHn + row] = cp;
      }
    }
  }
  float* Ao = Abar + (((long)(c*NH + h)) * 64 + row) * 64 + c0;
  float* Co = Cbar + (((long)(c*NH + h)) * 64 + row) * 64 + c0;
  *(float4*)&Ao[0] = *(float4*)&M[0];
  *(float4*)&Ao[4] = *(float4*)&M[4];
  *(float4*)&Co[0] = *(float4*)&Nn[0];
  *(float4*)&Co[4] = *(float4*)&Nn[4];
}

// ---------------------------------------------------------------------------
// K5b: state-only chunk scan with register double-buffer prefetch.
// ---------------------------------------------------------------------------
__global__ __launch_bounds__(64, 1) void k_scan(
    const float* __restrict__ Abar, const float* __restrict__ Cbar,
    const float* __restrict__ S0, float* __restrict__ Sst)
{
  const int h = blockIdx.x >> 6, m = blockIdx.x & 63, d = threadIdx.x;
  float s = S0[((long)h*DHn + m)*DHn + d];
  float a0[64], a1[64];
  float cb0, cb1;

#define PREF_(AR, CB, CI) do { \
    const float* Ac_ = Abar + ((long)(CI)*NH + h) * 4096; \
    _Pragma("unroll") \
    for (int l = 0; l < 64; ++l) AR[l] = Ac_[l*64 + d]; \
    CB = Cbar[((long)(CI)*NH + h) * 4096 + m*64 + d]; \
  } while (0)

#define STEP_(AR, CB) do { \
    float n0 = 0.f, n1 = 0.f, n2 = 0.f, n3 = 0.f; \
    _Pragma("unroll") \
    for (int l = 0; l < 16; ++l) { \
      n0 = fmaf(rdlane(s, l),      AR[l],      n0); \
      n1 = fmaf(rdlane(s, 16 + l), AR[16 + l], n1); \
      n2 = fmaf(rdlane(s, 32 + l), AR[32 + l], n2); \
      n3 = fmaf(rdlane(s, 48 + l), AR[48 + l], n3); \
    } \
    s = ((n0 + n1) + (n2 + n3)) + CB; \
  } while (0)

  PREF_(a0, cb0, 0);
  #pragma unroll 1
  for (int c = 0; c < NC; c += 2) {
    PREF_(a1, cb1, c + 1);
    Sst[(((long)c*NH + h)*64 + m)*64 + d] = s;
    STEP_(a0, cb0);
    const int cn = (c + 2 < NC) ? (c + 2) : (NC - 1);
    PREF_(a0, cb0, cn);
    Sst[(((long)(c+1)*NH + h)*64 + m)*64 + d] = s;
    STEP_(a1, cb1);
  }
#undef PREF_
#undef STEP_
}

// ---------------------------------------------------------------------------
// K5c: parallel output eval -> bf16 Y (operand of the Wo GEMM).
// ---------------------------------------------------------------------------
__global__ __launch_bounds__(256, 1) void k_yout(
    const float* __restrict__ Sst, const float* __restrict__ zbuf,
    const float* __restrict__ cbuf, ushort* __restrict__ Y)
{
  const int c = blockIdx.x, h = blockIdx.y;
  const int tid = threadIdx.x, m = tid & 63, tg = tid >> 6;
  __shared__ float Zl[CL][DHn];
  {
    const float4* Zc = (const float4*)(zbuf + ((long)h*Tn + c*CL) * DHn);
    ((float4*)&Zl[0][0])[tid] = Zc[tid];
  }
  const float* Srow = Sst + (((long)c*NH + h)*64 + m) * 64;
  float sr[64];
  #pragma unroll
  for (int q4 = 0; q4 < 16; ++q4)
    *(float4*)&sr[q4*4] = ((const float4*)Srow)[q4];
  __syncthreads();
  const float* Cc = cbuf + ((long)h*Tn + c*CL) * DHn;
  #pragma unroll
  for (int it = 0; it < 4; ++it) {
    const int tt = tg*4 + it;
    float y = 0.f;
    #pragma unroll
    for (int l = 0; l < 64; ++l) y = fmaf(sr[l], Zl[tt][l], y);
    Y[((long)(c*CL + tt))*Dn + h*DHn + m] = f2bf(y + Cc[tt*DHn + m]);
  }
}

// ---------------------------------------------------------------------------
extern "C" void kernel_launch(void* const* d_in, const int* in_sizes, int n_in,
                              void* d_out, int out_size, void* d_ws, size_t ws_size,
                              hipStream_t stream)
{
  const float* x   = (const float*)d_in[0];
  const float* pw  = (const float*)d_in[1];
  const float* Wq  = (const float*)d_in[2];
  const float* Wk  = (const float*)d_in[3];
  const float* Wv  = (const float*)d_in[4];
  const float* Wo  = (const float*)d_in[5];
  const float* qcw = (const float*)d_in[6];
  const float* kcw = (const float*)d_in[7];
  const float* vcw = (const float*)d_in[8];
  const float* lrw = (const float*)d_in[9];
  const float* lrb = (const float*)d_in[10];
  const float* dw  = (const float*)d_in[11];
  const float* db  = (const float*)d_in[12];
  const float* gw  = (const float*)d_in[13];
  const float* gb  = (const float*)d_in[14];
  const float* qg  = (const float*)d_in[15];
  const float* kg  = (const float*)d_in[16];
  const float* S0  = (const float*)d_in[17];
  float* out = (float*)d_out;
  float* ws  = (float*)d_ws;

  const long N = (long)Tn * Dn;   // 262144 floats per 512x512 fp32 matrix
  float*  xn    = ws;
  ushort* qkvbf = (ushort*)(ws + 1*N);
  float*  Abar  = ws;
  float*  Cbar  = ws + 4*N;
  float*  Qb    = ws + 8*N;
  float*  Sst   = ws + 8*N;
  float*  zbuf  = ws + 12*N;
  float*  cbuf  = ws + 13*N;
  ushort* Wbf   = (ushort*)(ws + 14*N);
  ushort* Ybf   = (ushort*)(ws + 16*N);
  float*  wgt   = ws + 16*N + N/2;    // [NH][T]
  float*  dcb   = wgt + NH*Tn;        // [NH][T]

  k_norm_gates<<<Tn, 256, 0, stream>>>(x, pw, lrw, lrb, dw, db, gw, gb,
                                       xn, wgt, dcb);
  k_cvt_w<<<dim3(256, 4), 256, 0, stream>>>(Wq, Wk, Wv, Wo, Wbf);
  k_conv<<<Tn, Dn, 0, stream>>>(xn, qcw, kcw, vcw,
                                qkvbf, qkvbf + NW, qkvbf + 2*NW);
  k_gemm_bf<<<dim3(16, 8, 3), 128, 0, stream>>>(qkvbf, NW, Wbf, NW,
                                                Qb, N, qg, kg);
  k_chunk<<<dim3(NC, NH), 512, 0, stream>>>(Qb, Qb + N, Qb + 2*N, wgt, dcb,
                                            Abar, Cbar, zbuf, cbuf);
  k_scan<<<NH * DHn, 64, 0, stream>>>(Abar, Cbar, S0, Sst);
  k_yout<<<dim3(NC, NH), 256, 0, stream>>>(Sst, zbuf, cbuf, Ybf);
  k_gemm_bf<<<dim3(16, 8, 1), 128, 0, stream>>>(Ybf, 0, Wbf + 3*NW, 0,
                                                out, 0, nullptr, nullptr);
}